// Round 6
// baseline (4592.171 us; speedup 1.0000x reference)
//
#include <hip/hip_runtime.h>
#include <stdint.h>
#include <math.h>

typedef unsigned int u32;
typedef unsigned long long u64;

#define Bb 4
#define Nn 8192
#define Dd 64
#define Kk 32
#define MAXIT 30
#define NCH   32     // chunks per batch (256 points each)
#define NBLK  128    // 4 batches x 32 chunks
#define NTHR  256

// ---- workspace layout (bytes); total ~5.51 MB ----
enum : u32 {
  WS_CONV = 0u,        // u32 convergence flag
  WS_CNT  = 128u,      // u32 last-block counter
  WS_CCL  = 256u,      // [4][32] f
  WS_CW   = 1024u,     // [4][32][64] f
  WS_XH   = 33792u,    // [4][32][64] f
  WS_MSK  = 66560u,    // [4][8192] u32
  WS_PCHG = 197632u,   // [128] u32
  WS_PCNT = 198144u,   // [4][32][32] u32
  WS_POBJ = 214528u,   // [4][32] f
  WS_PMIN = 215040u,   // [4][32 k][32 c] u64
  WS_PSUM = 247040u,   // [4][32][2080] f (also aliased as sort scratch in kinit)
  WS_DM   = 1312000u   // [4][32][8192] f final distances (store-and-compare; R5 lesson)
};
// kinit-only aliases inside WS_PSUM region:
enum : u32 {
  SS_K1 = WS_PSUM +      0u,
  SS_K2 = WS_PSUM +  32768u,
  SS_AK1= WS_PSUM +  65536u,
  SS_AV1= WS_PSUM +  98304u,
  SS_AK2= WS_PSUM + 131072u,
  SS_AV2= WS_PSUM + 163840u
};

// Threefry-2x32, 20 rounds — jax threefry_partitionable semantics
__device__ __forceinline__ void tf2x32(u32 k0, u32 k1, u32 x0, u32 x1, u32& o0, u32& o1){
  u32 ks2 = k0 ^ k1 ^ 0x1BD11BDAu;
  x0 += k0; x1 += k1;
#define TFR(r) { x0 += x1; x1 = (x1<<(r))|(x1>>(32-(r))); x1 ^= x0; }
  TFR(13) TFR(15) TFR(26) TFR(6)
  x0 += k1;  x1 += ks2 + 1u;
  TFR(17) TFR(29) TFR(16) TFR(24)
  x0 += ks2; x1 += k0 + 2u;
  TFR(13) TFR(15) TFR(26) TFR(6)
  x0 += k0;  x1 += k1 + 3u;
  TFR(17) TFR(29) TFR(16) TFR(24)
  x0 += k1;  x1 += ks2 + 4u;
  TFR(13) TFR(15) TFR(26) TFR(6)
  x0 += ks2; x1 += k0 + 5u;
#undef TFR
  o0 = x0; o1 = x1;
}

__device__ __forceinline__ u32 fenc(float f){ u32 u=__float_as_uint(f); return (u&0x80000000u)? ~u : (u|0x80000000u); }
__device__ __forceinline__ float fdec(u32 u){ u32 v=(u&0x80000000u)? (u&0x7fffffffu) : ~u; return __uint_as_float(v); }

// ---------------- init: PRNG + 2 stable sorts + Cw/ccl/XH/Msk/flags ----------------
__global__ __launch_bounds__(1024, 1) void kinit(const float* __restrict__ E, char* __restrict__ ws){
  const int tid = threadIdx.x;
  u32* conv  = (u32*)(ws + WS_CONV);
  u32* cntr  = (u32*)(ws + WS_CNT);
  u32* Msk   = (u32*)(ws + WS_MSK);
  u32* keys1 = (u32*)(ws + SS_K1);
  u32* keys2 = (u32*)(ws + SS_K2);
  u32* a1k = (u32*)(ws + SS_AK1); u32* a1v = (u32*)(ws + SS_AV1);
  u32* a2k = (u32*)(ws + SS_AK2); u32* a2v = (u32*)(ws + SS_AV2);
  float* Cw = (float*)(ws + WS_CW);
  float* XH = (float*)(ws + WS_XH);
  float* cclw = (float*)(ws + WS_CCL);

  __shared__ u32 hist[8192];
  __shared__ u32 lsum[1024];
  __shared__ u32 sel_s[32];

  if (tid == 0){ conv[0] = 0u; cntr[0] = 0u; }
  for (int i = tid; i < Bb*Nn; i += 1024) Msk[i] = 0u;

  // key chain: root=(0,42); k_init=enc(0,0); key1=enc_kinit(0,0); sub1=enc_kinit(0,1); sub2=enc_key1(0,1)
  u32 i0,i1; tf2x32(0u,42u, 0u,0u, i0,i1);
  u32 key10,key11, s10,s11;
  tf2x32(i0,i1, 0u,0u, key10,key11);
  tf2x32(i0,i1, 0u,1u, s10,s11);
  u32 s20,s21; tf2x32(key10,key11, 0u,1u, s20,s21);

  for (int i = tid; i < 8192; i += 1024){
    u32 y0,y1;
    tf2x32(s10,s11, 0u,(u32)i, y0,y1); keys1[i] = y0 ^ y1;
    tf2x32(s20,s21, 0u,(u32)i, y0,y1); keys2[i] = y0 ^ y1;
  }
  for (int i = tid; i < 8192; i += 1024){
    int b = i >> 11; int rem = i & 2047;
    XH[i] = E[(size_t)b*Nn*Dd + rem];
  }
  __syncthreads();

  for (int rnd = 0; rnd < 2; rnd++){
    u32* keys = rnd ? keys2 : keys1;
    u32* ak   = rnd ? a2k   : a1k;
    u32* av   = rnd ? a2v   : a1v;
    for (int i = tid; i < 8192; i += 1024) hist[i] = 0u;
    __syncthreads();
    for (int i = tid; i < 8192; i += 1024) atomicAdd(&hist[keys[i]>>19], 1u);
    __syncthreads();
    { u32 s = 0;
      for (int j = 0; j < 8; j++) s += hist[tid*8+j];
      lsum[tid] = s; }
    __syncthreads();
    for (int st = 1; st < 1024; st <<= 1){
      u32 v = (tid >= st) ? lsum[tid-st] : 0u;
      __syncthreads();
      lsum[tid] += v;
      __syncthreads();
    }
    { u32 run = tid ? lsum[tid-1] : 0u;
      for (int j = 0; j < 8; j++){ u32 c = hist[tid*8+j]; hist[tid*8+j] = run; run += c; } }
    __syncthreads();
    for (int i = tid; i < 8192; i += 1024){
      u32 kx = keys[i];
      u32 pos = atomicAdd(&hist[kx>>19], 1u);
      ak[pos] = kx; av[pos] = (u32)i;
    }
    __syncthreads();
    for (int bkt = tid; bkt < 8192; bkt += 1024){
      int s0 = bkt ? (int)hist[bkt-1] : 0;
      int e0 = (int)hist[bkt];
      for (int i = s0+1; i < e0; i++){
        u32 kx = ak[i], vx = av[i];
        int j = i-1;
        while (j >= s0 && (ak[j] > kx || (ak[j] == kx && av[j] > vx))){
          ak[j+1] = ak[j]; av[j+1] = av[j]; j--;
        }
        ak[j+1] = kx; av[j+1] = vx;
      }
    }
    __syncthreads();
  }
  if (tid < 32){ u32 p = a2v[tid]; sel_s[tid] = a1v[p]; }
  __syncthreads();
  for (int i = tid; i < Bb*Kk*Dd; i += 1024){
    int b = i >> 11; int k = (i >> 6) & 31; int d = i & 63;
    Cw[i] = E[(size_t)b*Nn*Dd + (size_t)sel_s[k]*Dd + d];
  }
  __syncthreads();   // Cw fully written before cclw reads it (R3 lesson)
  if (tid < 128){
    int b = tid >> 5, k = tid & 31;
    const float* cr = &Cw[0] + (b*32 + k)*64;
    float s = 0.f;
    for (int d = 0; d < 64; d++) s += cr[d]*cr[d];
    cclw[tid] = s;
  }
}

#define CALC_XX() do { float s0=0.f,s1=0.f,s2=0.f,s3=0.f; \
  _Pragma("unroll") \
  for (int j=0;j<16;j++){ s0+=x[4*j]*x[4*j]; s1+=x[4*j+1]*x[4*j+1]; s2+=x[4*j+2]*x[4*j+2]; s3+=x[4*j+3]*x[4*j+3]; } \
  xx=(s0+s1)+(s2+s3); } while(0)

// single-k distance
#define DIST_K(cp, cck, dst) do { \
  float s0=0.f,s1=0.f,s2=0.f,s3=0.f; \
  _Pragma("unroll") \
  for (int q=0;q<16;q++){ float4 c = (cp)[q]; s0+=x[4*q]*c.x; s1+=x[4*q+1]*c.y; s2+=x[4*q+2]*c.z; s3+=x[4*q+3]*c.w; } \
  float dot=(s0+s1)+(s2+s3); \
  (dst)=((cck)+xx)-2.f*dot; } while(0)

#define LOAD_POINT() do { \
  const float* xsrc = (n < 32) ? (XH + (size_t)(b*32 + n)*64) : (E + (size_t)(b*Nn + n)*Dd); \
  const float4* xr = (const float4*)xsrc; \
  _Pragma("unroll") \
  for (int j=0;j<16;j++){ float4 v = xr[j]; x[4*j]=v.x; x[4*j+1]=v.y; x[4*j+2]=v.z; x[4*j+3]=v.w; } } while(0)

// ---------------- K_STEP: one full iteration (128 blocks x 256 thr; last block updates) ----
__global__ __launch_bounds__(NTHR) void k_step(const float* __restrict__ E, const float* __restrict__ LW,
                                               char* __restrict__ ws, int t){
  u32* conv = (u32*)(ws + WS_CONV);
  if (conv[0]) return;
  const int tid = threadIdx.x;
  const int bid = blockIdx.x;
  const int b   = bid >> 5;
  const int c   = bid & 31;
  const int n   = (c << 8) + tid;

  u32*   cntr = (u32*)(ws + WS_CNT);
  float* Cw   = (float*)(ws + WS_CW);
  float* cclw = (float*)(ws + WS_CCL);
  float* XH   = (float*)(ws + WS_XH);
  u32*   Msk  = (u32*)(ws + WS_MSK);
  u32*   Pchg = (u32*)(ws + WS_PCHG);
  u32*   Pcnt = (u32*)(ws + WS_PCNT);
  float* Psum = (float*)(ws + WS_PSUM);

  __shared__ float Cl[2048];     // C[k][d] k-major; reused as fixup/C staging in tail
  __shared__ float ccl[32];
  __shared__ float part[2080];   // d-major: part[d*32+k]; W at 2048+k; reused in tail
  __shared__ u32   cntl[32];
  __shared__ u32   sh_last;

  { float4* c4 = (float4*)Cl; const float4* g4 = (const float4*)(Cw + b*2048);
    for (int i = tid; i < 512; i += NTHR) c4[i] = g4[i]; }
  if (tid < 32) ccl[tid] = cclw[b*32 + tid];
  for (int i = tid; i < 2080; i += NTHR) part[i] = 0.f;
  if (tid < 32) cntl[tid] = 0u;

  float x[64]; float xx;
  LOAD_POINT();
  CALC_XX();
  const float w = expf(LW[b*Nn + n]);
  __syncthreads();

  float dloc[32];
  #pragma unroll
  for (int k = 0; k < 32; k++){
    const float4* cp = (const float4*)&Cl[k*64];
    DIST_K(cp, ccl[k], dloc[k]);
  }
  float mind = dloc[0];
  #pragma unroll
  for (int k=1;k<32;k++) mind = fminf(mind, dloc[k]);
  u32 mask = 0u;
  #pragma unroll
  for (int k=0;k<32;k++) if (fabsf(dloc[k]-mind) < 1e-8f) mask |= (1u<<k);
  int changed = (mask != Msk[b*Nn + n]);
  Msk[b*Nn + n] = mask;

  { u32 mm = mask;
    while (mm){
      int k = __ffs(mm) - 1; mm &= mm - 1;
      #pragma unroll
      for (int d2=0; d2<64; d2++) atomicAdd(&part[d2*32 + k], w*x[d2]);
      atomicAdd(&part[2048 + k], w);
      atomicAdd(&cntl[k], 1u);
    } }
  int nchg = __syncthreads_count(changed);

  { float* dst = Psum + (size_t)(b*32 + c)*2080;
    for (int e = tid; e < 2080; e += NTHR) dst[e] = part[e];
    if (tid < 32) Pcnt[(b*32 + c)*32 + tid] = cntl[tid];
    if (tid == 0) Pchg[bid] = (u32)nchg; }

  // ---- last-block-done: release partials, count arrivals ----
  __threadfence();
  if (tid == 0){
    u32 old = __hip_atomic_fetch_add(cntr, 1u, __ATOMIC_ACQ_REL, __HIP_MEMORY_SCOPE_AGENT);
    sh_last = (old == (u32)(NBLK-1)) ? 1u : 0u;
  }
  __syncthreads();
  if (!sh_last) return;
  __threadfence();   // acquire: other blocks' Psum/Pcnt/Pchg now visible

  // ---- tail: convergence, per-batch reduce + fixup + C update ----
  { u32 v = (tid < NBLK) ? Pchg[tid] : 0u;
    int anych = __syncthreads_count(v != 0u);
    if (anych == 0){
      if (tid == 0){ conv[0] = 1u; cntr[0] = 0u; }
      return;
    } }

  u32 kl0, kl1; tf2x32(0u,42u, 0u,1u, kl0, kl1);
  u32 g0, g1;  tf2x32(kl0, kl1, 0u, (u32)t, g0, g1);   // fold_in(k_loop, t)

  for (int b2 = 0; b2 < Bb; b2++){
    // deterministic chunk-ascending reduce
    { const float* src = Psum + (size_t)(b2*32)*2080;
      for (int e = tid; e < 2080; e += NTHR){
        float s = 0.f;
        for (int cc = 0; cc < 32; cc++) s += src[(size_t)cc*2080 + e];
        part[e] = s;
      } }
    u32 myc = 1u;
    if (tid < 32){
      u32 s = 0;
      for (int cc = 0; cc < 32; cc++) s += Pcnt[(b2*32 + cc)*32 + tid];
      cntl[tid] = s; myc = s;
    }
    int nempty = __syncthreads_count(tid < 32 && myc == 0u);

    if (nempty){
      // gather replacement rows (pre-replacement X) + adjust sums, then commit
      for (int k = 0; k < 32; k++){
        if (cntl[k] != 0u) continue;
        int j = b2*32 + k;
        u32 y0, y1; tf2x32(g0, g1, 0u, (u32)j, y0, y1);
        u32 ridx = (y0 ^ y1) & 8191u;
        u32 mj = Msk[b2*Nn + k];
        float wj = expf(LW[b2*Nn + k]);
        if (tid < 64){
          float xo = XH[(b2*32 + k)*64 + tid];
          float xn = (ridx < 32u) ? XH[(b2*32 + (int)ridx)*64 + tid]
                                  : E[(size_t)(b2*Nn + (int)ridx)*Dd + tid];
          Cl[k*64 + tid] = xn;     // staging
          float dxw = wj * (xn - xo);
          u32 m2 = mj;
          while (m2){ int kq = __ffs(m2) - 1; m2 &= m2 - 1; part[tid*32 + kq] += dxw; }
        }
        __syncthreads();
      }
      for (int k = 0; k < 32; k++){
        if (cntl[k] != 0u) continue;
        if (tid < 64) XH[(b2*32 + k)*64 + tid] = Cl[k*64 + tid];
      }
      __syncthreads();
    }

    // C_new = sums / clip(W,1e-12); stage in Cl, write Cw + ccl
    for (int i = tid; i < 2048; i += NTHR){
      int k = i >> 6, d = i & 63;
      Cl[i] = part[d*32 + k] / fmaxf(part[2048 + k], 1e-12f);
    }
    __syncthreads();
    for (int i = tid; i < 2048; i += NTHR) Cw[b2*2048 + i] = Cl[i];
    if (tid < 32){
      float s = 0.f; const float* cr = &Cl[tid*64];
      for (int d = 0; d < 64; d++) s += cr[d]*cr[d];
      cclw[b2*32 + tid] = s;
    }
    __syncthreads();
  }
  if (tid == 0) cntr[0] = 0u;
}

// ---------------- KF1: ass out + Dm store + per-chunk mins/obj (128 blocks x 256 thr) ----
__global__ __launch_bounds__(NTHR) void k_fin1(const float* __restrict__ E,
                                               float* __restrict__ out, char* __restrict__ ws){
  const int tid = threadIdx.x;
  const int bid = blockIdx.x;
  const int b   = bid >> 5;
  const int c   = bid & 31;
  const int n   = (c << 8) + tid;

  const float* Cw   = (const float*)(ws + WS_CW);
  const float* cclw = (const float*)(ws + WS_CCL);
  const float* XH   = (const float*)(ws + WS_XH);
  const u32*   Msk  = (const u32*)(ws + WS_MSK);
  float* Pobj = (float*)(ws + WS_POBJ);
  u64*   Pmin = (u64*)(ws + WS_PMIN);
  float* Dm   = (float*)(ws + WS_DM);

  __shared__ float Cl[2048];
  __shared__ float ccl[32];
  __shared__ u64   kminl[32];
  __shared__ float red[NTHR];

  { float4* c4 = (float4*)Cl; const float4* g4 = (const float4*)(Cw + b*2048);
    for (int i = tid; i < 512; i += NTHR) c4[i] = g4[i]; }
  if (tid < 32){ ccl[tid] = cclw[b*32 + tid]; kminl[tid] = ~0ull; }

  float x[64]; float xx;
  LOAD_POINT();
  CALC_XX();
  __syncthreads();

  // streaming k-loop: store dk to Dm (no dloc array -> no spill; R5 lesson: store-and-compare)
  float mind = 0.f;
  #pragma unroll
  for (int k = 0; k < 32; k++){
    const float4* cp = (const float4*)&Cl[k*64];
    float dk; DIST_K(cp, ccl[k], dk);
    Dm[(size_t)(b*32 + k)*Nn + n] = dk;
    mind = (k == 0) ? dk : fminf(mind, dk);
    u64 pk = ((u64)fenc(dk) << 32) | (u32)n;
    atomicMin(&kminl[k], pk);
  }

  // ass = frozen last assignment
  { u32 msk = Msk[b*Nn + n];
    float4* dst = (float4*)(out + (size_t)(b*Nn + n)*32);
    #pragma unroll
    for (int q=0;q<8;q++){
      float4 vv;
      vv.x = ((msk>>(4*q  ))&1u) ? 1.f : 0.f;
      vv.y = ((msk>>(4*q+1))&1u) ? 1.f : 0.f;
      vv.z = ((msk>>(4*q+2))&1u) ? 1.f : 0.f;
      vv.w = ((msk>>(4*q+3))&1u) ? 1.f : 0.f;
      dst[q] = vv;
    } }

  red[tid] = mind;
  __syncthreads();
  for (int s2 = 128; s2 > 0; s2 >>= 1){
    if (tid < s2) red[tid] += red[tid + s2];
    __syncthreads();
  }
  if (tid < 32) Pmin[(size_t)(b*32 + tid)*32 + c] = kminl[tid];
  if (tid == 0) Pobj[b*32 + c] = red[0];
}

// ---------------- KF2: rep/rep_idx/C/obj from STORED Dm (128 blocks x 256 thr) ----------
__global__ __launch_bounds__(NTHR) void k_fin2(const float* __restrict__ E,
                                               float* __restrict__ out, char* __restrict__ ws){
  const int tid = threadIdx.x;
  const int bid = blockIdx.x;
  const int b   = bid >> 5;
  const int k   = bid & 31;

  const float* Cw   = (const float*)(ws + WS_CW);
  const float* XH   = (const float*)(ws + WS_XH);
  const float* Pobj = (const float*)(ws + WS_POBJ);
  const u64*   Pmin = (const u64*)(ws + WS_PMIN);
  const float* Dm   = (const float*)(ws + WS_DM);

  __shared__ float acc[64];
  __shared__ float red[64];
  __shared__ u32   sh_cnt, sh_idx;
  __shared__ float sh_mind;

  if (tid < 64) acc[tid] = 0.f;
  if (tid == 0){
    u64 m = ~0ull;
    for (int c = 0; c < 32; c++){ u64 vv = Pmin[(size_t)(b*32 + k)*32 + c]; if (vv < m) m = vv; }
    sh_mind = fdec((u32)(m >> 32));
    sh_idx  = (u32)(m & 0xffffffffu);
    sh_cnt  = 0u;
  }
  __syncthreads();
  const float gmd  = sh_mind;
  const float* DmR = Dm + (size_t)(b*32 + k)*Nn;

  for (int nn = tid; nn < Nn; nn += NTHR){
    float dv = DmR[nn];
    if (fabsf(dv - gmd) < 1e-8f){
      atomicAdd(&sh_cnt, 1u);
      const float* xr = (nn < 32) ? (XH + (size_t)(b*32 + nn)*64) : (E + (size_t)(b*Nn + nn)*Dd);
      for (int d = 0; d < 64; d++) atomicAdd(&acc[d], xr[d]);
    }
  }
  __syncthreads();

  const size_t OFF_C    = (size_t)Bb*Nn*Kk;
  const size_t OFF_REP  = OFF_C + (size_t)Bb*Kk*Dd;
  const size_t OFF_RIDX = OFF_REP + (size_t)Bb*Kk*Dd;
  const size_t OFF_OBJ  = OFF_RIDX + (size_t)Bb*Kk;
  if (tid < 64){
    out[OFF_C   + (size_t)(b*32 + k)*64 + tid] = Cw[(size_t)(b*32 + k)*64 + tid];
    out[OFF_REP + (size_t)(b*32 + k)*64 + tid] = acc[tid] / (float)sh_cnt;
  }
  if (tid == 0) out[OFF_RIDX + b*32 + k] = (float)sh_idx;
  if (k == 0){
    if (tid < 32) red[tid] = Pobj[b*32 + tid];
    __syncthreads();
    if (tid == 0){
      float s = 0.f;
      for (int i = 0; i < 32; i++) s += red[i];
      out[OFF_OBJ + b] = s / (float)Nn;
    }
  }
}

extern "C" void kernel_launch(void* const* d_in, const int* in_sizes, int n_in,
                              void* d_out, int out_size, void* d_ws, size_t ws_size,
                              hipStream_t stream) {
  const float* E  = (const float*)d_in[0];
  const float* LW = (const float*)d_in[1];
  float* out = (float*)d_out;
  char*  ws  = (char*)d_ws;
  (void)in_sizes; (void)n_in; (void)out_size; (void)ws_size;

  kinit<<<dim3(1), dim3(1024), 0, stream>>>(E, ws);
  for (int t = 0; t < MAXIT; t++){
    k_step<<<dim3(NBLK), dim3(NTHR), 0, stream>>>(E, LW, ws, t);
  }
  k_fin1<<<dim3(NBLK), dim3(NTHR), 0, stream>>>(E, out, ws);
  k_fin2<<<dim3(NBLK), dim3(NTHR), 0, stream>>>(E, out, ws);
}